// Round 1
// baseline (73.171 us; speedup 1.0000x reference)
//
#include <hip/hip_runtime.h>

// Problem constants (from reference setup_inputs):
//   pred_masks:   [B=8, NP=8, 512, 512] f32 logits
//   target_masks: [B=8, NT=16, 512, 512] f32 in [0,1]
// Output: single f32 scalar.
#define NB 8
#define NP 8
#define NT 16
#define HW (512 * 512)
#define HW4 (HW / 4)              // 65536 float4 per image
#define NACC (NP + NP * NT + NT)  // 8 + 128 + 16 = 152 accumulators per batch
#define BLOCKS_PER_B 64
#define THREADS 256
#define ITERS 4                   // 64 blocks * 256 thr * 4 iters = 65536 = HW4

__device__ __forceinline__ float wred(float v) {
#pragma unroll
  for (int off = 32; off > 0; off >>= 1) v += __shfl_down(v, off);
  return v;
}

__device__ __forceinline__ float softplus1(float x) {
  // stable: max(x,0) + log(1 + exp(-|x|)); fast hw exp/log, err ~1e-6 rel.
  return fmaxf(x, 0.0f) + __logf(1.0f + __expf(-fabsf(x)));
}

__device__ __forceinline__ float sp4(float4 p) {
  return (softplus1(p.x) + softplus1(p.y)) + (softplus1(p.z) + softplus1(p.w));
}

// Stage 1: per-block partial sums of {softplus sums [NP], dots [NP][NT],
// target sums [NT]} for one batch, atomically added into ws[b][NACC].
__global__ __launch_bounds__(THREADS, 2) void sam_partial(
    const float* __restrict__ pred, const float* __restrict__ targ,
    float* __restrict__ ws) {
  const int b   = blockIdx.x / BLOCKS_PER_B;
  const int blk = blockIdx.x % BLOCKS_PER_B;
  const int tid = threadIdx.x;

  float sp[NP];
  float ts[NT];
  float dot[NP][NT];
#pragma unroll
  for (int i = 0; i < NP; ++i) sp[i] = 0.0f;
#pragma unroll
  for (int j = 0; j < NT; ++j) ts[j] = 0.0f;
#pragma unroll
  for (int i = 0; i < NP; ++i)
#pragma unroll
    for (int j = 0; j < NT; ++j) dot[i][j] = 0.0f;

  const float4* __restrict__ pb =
      reinterpret_cast<const float4*>(pred) + (size_t)b * NP * HW4;
  const float4* __restrict__ tb =
      reinterpret_cast<const float4*>(targ) + (size_t)b * NT * HW4;

#pragma unroll 1
  for (int it = 0; it < ITERS; ++it) {
    const int idx = blk * (THREADS * ITERS) + it * THREADS + tid;
    float4 p[NP];
#pragma unroll
    for (int i = 0; i < NP; ++i) p[i] = pb[(size_t)i * HW4 + idx];
#pragma unroll
    for (int i = 0; i < NP; ++i) sp[i] += sp4(p[i]);
#pragma unroll
    for (int j = 0; j < NT; ++j) {
      float4 t = tb[(size_t)j * HW4 + idx];
      ts[j] += (t.x + t.y) + (t.z + t.w);
#pragma unroll
      for (int i = 0; i < NP; ++i) {
        dot[i][j] = fmaf(p[i].x, t.x,
                    fmaf(p[i].y, t.y,
                    fmaf(p[i].z, t.z,
                    fmaf(p[i].w, t.w, dot[i][j]))));
      }
    }
  }

  // Block reduction: wave shuffle-reduce each accumulator, stash wave sums in
  // LDS, then threads 0..NACC-1 fold 4 waves and atomicAdd to global ws.
  __shared__ float red[4][NACC];
  const int lane = tid & 63;
  const int wid  = tid >> 6;

#pragma unroll
  for (int i = 0; i < NP; ++i) {
    float v = wred(sp[i]);
    if (lane == 0) red[wid][i] = v;
  }
#pragma unroll
  for (int i = 0; i < NP; ++i) {
#pragma unroll
    for (int j = 0; j < NT; ++j) {
      float v = wred(dot[i][j]);
      if (lane == 0) red[wid][NP + i * NT + j] = v;
    }
  }
#pragma unroll
  for (int j = 0; j < NT; ++j) {
    float v = wred(ts[j]);
    if (lane == 0) red[wid][NP + NP * NT + j] = v;
  }
  __syncthreads();
  if (tid < NACC) {
    float v = (red[0][tid] + red[1][tid]) + (red[2][tid] + red[3][tid]);
    atomicAdd(ws + (size_t)b * NACC + tid, v);
  }
}

// Stage 2: one wave; thread t owns (b = t>>3, i = t&7). Computes
// min_j(empty_j ? 0 : (spsum - dotsum)/HW), then mean over 64, * 5.
__global__ void sam_final(const float* __restrict__ ws,
                          float* __restrict__ out) {
  const int t = threadIdx.x;  // 64 threads
  const int b = t >> 3;
  const int i = t & 7;
  const float* w = ws + (size_t)b * NACC;
  const float spsum = w[i];
  float m = 3.4e38f;
#pragma unroll
  for (int j = 0; j < NT; ++j) {
    const float tsj = w[NP + NP * NT + j];
    const float v =
        (tsj == 0.0f) ? 0.0f : (spsum - w[NP + i * NT + j]) * (1.0f / HW);
    m = fminf(m, v);
  }
  const float s = wred(m);
  if (t == 0) out[0] = 5.0f * s * (1.0f / 64.0f);
}

extern "C" void kernel_launch(void* const* d_in, const int* in_sizes, int n_in,
                              void* d_out, int out_size, void* d_ws,
                              size_t ws_size, hipStream_t stream) {
  const float* pred = (const float*)d_in[0];
  const float* targ = (const float*)d_in[1];
  float* out = (float*)d_out;
  float* ws = (float*)d_ws;

  hipMemsetAsync(ws, 0, (size_t)NB * NACC * sizeof(float), stream);
  sam_partial<<<dim3(NB * BLOCKS_PER_B), THREADS, 0, stream>>>(pred, targ, ws);
  sam_final<<<1, 64, 0, stream>>>(ws, out);
}